// Round 7
// baseline (3115.670 us; speedup 1.0000x reference)
//
#include <hip/hip_runtime.h>
#include <hip/hip_bf16.h>
#include <math.h>

#define NEGF (-1000000000.0f)

constexpr int Bc = 8;
constexpr int Sc = 64;
constexpr int Hc = 512;
constexpr int Tc = 17;
constexpr int TRIc = Sc*(Sc+1)/2;     // 2080

typedef __bf16 bf16x8 __attribute__((ext_vector_type(8)));
typedef float  f32x4  __attribute__((ext_vector_type(4)));

__device__ __forceinline__ int tri_idx(int i, int j){
  return i*Sc - (i*(i-1))/2 + (j - i);
}

// (i,j) position + activity for (pass, row r, step k, length L)
__device__ __forceinline__ void posmap(int pass, int r, int k, int L,
                                       int& i, int& j, bool& act){
  if      (pass == 0){ act = (r < L - k);            i = r;     j = L - 1 - k; }
  else if (pass == 1){ act = (r < L - k);            i = r;     j = r + k;     }
  else if (pass == 2){ act = (r >= k) && (r < L);    i = r - k; j = r;         }
  else               { act = (r >= k) && (r < L);    i = k;     j = r;         }
  if (!act){ i = 0; j = 0; }
}

__device__ __forceinline__ float pt_val(const float* __restrict__ pt_acc,
                                        const float* __restrict__ btv,
                                        int b, int t, int i, int j, int L){
  const bool masked = (i > j) || (j >= L) ||
                      (t < Tc-1 && i == j) || (t == Tc-1 && i < j);
  if (masked) return NEGF;
  return pt_acc[(((size_t)b*Tc + t)*Sc + i)*Sc + j] + btv[t];
}

// ---------------------------------------------------------------------------
__global__ __launch_bounds__(256) void k_cvt(const float* __restrict__ s,
                                             __hip_bfloat16* __restrict__ d, int n4){
  int i = blockIdx.x*256 + threadIdx.x;
  if (i >= n4) return;
  float4 v = reinterpret_cast<const float4*>(s)[i];
  union { __hip_bfloat16 h[4]; ushort4 u; } p;
  p.h[0] = __float2bfloat16(v.x); p.h[1] = __float2bfloat16(v.y);
  p.h[2] = __float2bfloat16(v.z); p.h[3] = __float2bfloat16(v.w);
  reinterpret_cast<ushort4*>(d)[i] = p.u;
}

// ---------------------------------------------------------------------------
// Weight prepack: Wp[wset][us(32)][row(64)][k(1024)] bf16
//   row = g*16 + uu  <->  source row g*512 + us*16 + uu
//   k < 512 -> Whh[srow][k] ; k >= 512 -> Wih[srow][k-512]
// ---------------------------------------------------------------------------
__global__ __launch_bounds__(256) void k_pack(
    const float* __restrict__ Whh_f, const float* __restrict__ Wih_f,
    const float* __restrict__ Whh_b, const float* __restrict__ Wih_b,
    __hip_bfloat16* __restrict__ Wp)
{
  int idx = blockIdx.x*256 + threadIdx.x;   // 1,048,576 quads
  int k4  = idx & 255;
  int row = (idx >> 8) & 63;
  int us  = (idx >> 14) & 31;
  int ws  = idx >> 19;
  int g = row >> 4, uu = row & 15;
  int srow = g*512 + us*16 + uu;
  int k = k4*4;
  const float* src;
  if (ws == 0) src = (k < 512) ? Whh_f : Wih_f;
  else         src = (k < 512) ? Whh_b : Wih_b;
  float4 v = *reinterpret_cast<const float4*>(src + (size_t)srow*512 + (k & 511));
  union { __hip_bfloat16 h[4]; ushort4 u; } p;
  p.h[0] = __float2bfloat16(v.x); p.h[1] = __float2bfloat16(v.y);
  p.h[2] = __float2bfloat16(v.z); p.h[3] = __float2bfloat16(v.w);
  *reinterpret_cast<ushort4*>(Wp + (size_t)idx*4) = p.u;
}

// ---------------------------------------------------------------------------
// Persistent 4-pass LSTM. 256 blocks linear; group = bid&7 (one XCD per
// (pass,mhalf) sync-group under round-robin placement), member = bid>>3 = us.
// Per block: M=256 seq-rows (of its mhalf), N=64 (4 gates x 16 units), K=1024.
// W slice LDS-resident (XOR-swizzled (row&7)<<4); C in registers; flag-sync.
// ---------------------------------------------------------------------------
__global__ __launch_bounds__(512) void k_persist(
    const __hip_bfloat16* __restrict__ Wp,
    const float* __restrict__ bih_f, const float* __restrict__ bhh_f,
    const float* __restrict__ bih_b, const float* __restrict__ bhh_b,
    const __hip_bfloat16* __restrict__ svb, const float* __restrict__ Wt,
    const int* __restrict__ lens,
    __hip_bfloat16* __restrict__ H,
    float* __restrict__ pt_acc, int* __restrict__ cnt)
{
  const int lbid  = blockIdx.x;
  const int grp   = lbid & 7;     // XCD-aligned sync group
  const int us    = lbid >> 3;    // 0..31 : 16-unit slice
  const int mhalf = grp & 1;
  const int pass  = grp >> 1;
  const bool useF = (pass==0 || pass==3);
  const int wset  = useF ? 0 : 1;
  const float* b1 = useF ? bih_f : bih_b;
  const float* b2 = useF ? bhh_f : bhh_b;
  const int off_wt = (pass==0 || pass==2) ? 512 : 0;

  const int t = threadIdx.x, lane = t & 63, wv = t >> 6;
  const int c15 = lane & 15, qq = lane >> 4;

  __shared__ ushort Wlds[65536];   // 128 KiB: 64 rows x 2048B, XOR-swizzled

  // ---- one-time: W slice global -> LDS (swizzle (row&7)<<4 on byte addr) ----
  {
    const __hip_bfloat16* Wpb = Wp + (((size_t)wset*32 + us)*64)*1024;
    const int row = t >> 3, c8 = t & 7;
    const int swz = (row & 7) << 4;
    #pragma unroll
    for (int q=0; q<16; ++q){
      int4 v = *reinterpret_cast<const int4*>(Wpb + (size_t)row*1024 + c8*128 + q*8);
      *reinterpret_cast<int4*>((char*)Wlds + ((row*2048 + c8*256 + q*16) ^ swz)) = v;
    }
  }

  // ---- per-thread constants ----
  const int u = us*16 + c15;             // this thread's unit (cell/gate col)
  const float bsI = b1[u]        + b2[u];
  const float bsF = b1[512 + u]  + b2[512 + u];
  const float bsG = b1[1024 + u] + b2[1024 + u];
  const float bsO = b1[1536 + u] + b2[1536 + u];

  int rowT[2], Lm[2];                    // per m-tile: base global row, length
  #pragma unroll
  for (int mt=0; mt<2; ++mt){
    rowT[mt] = mhalf*256 + (wv*2 + mt)*16;
    Lm[mt]   = lens[rowT[mt] >> 6];
  }
  const int Lwave = (Lm[0] > Lm[1]) ? Lm[0] : Lm[1];

  const int rowP = mhalf*256 + us*8 + wv;        // projection row (1/wave)
  const int bP = rowP >> 6, rP = rowP & 63;
  const int LP = lens[bP];

  float creg[2][4];
  #pragma unroll
  for (int mt=0; mt<2; ++mt)
    #pragma unroll
    for (int e=0; e<4; ++e) creg[mt][e] = 0.f;

  const int gi_base = grp*64;
  const int lswz = (c15 & 7) << 4;       // read-side W swizzle
  __syncthreads();                       // Wlds ready

  for (int k=0; k<64; ++k){
    const int cur = k & 1;
    if (k < Lwave){
      const __hip_bfloat16* hp[2];
      const __hip_bfloat16* xp[2];
      #pragma unroll
      for (int mt=0; mt<2; ++mt){
        const int rg = rowT[mt] + c15;
        int i, j; bool a_;
        posmap(pass, rg & 63, k, Lm[mt], i, j, a_);
        hp[mt] = H + (((size_t)cur*4 + pass)*512 + rg)*512;
        xp[mt] = svb + ((size_t)(rg >> 6)*TRIc + tri_idx(i, j))*512;
      }

      f32x4 acc[2][4];                   // [mt][gate]
      #pragma unroll
      for (int mt=0; mt<2; ++mt)
        #pragma unroll
        for (int g=0; g<4; ++g) acc[mt][g] = f32x4{0.f,0.f,0.f,0.f};

      bf16x8 a0[2][2], a1[2][2], a2[2][2];   // [kk][mt], depth-2 pipeline
      {
        const int o0 = qq*8;
        const int o1 = 64 + qq*8;
        #pragma unroll
        for (int mt=0; mt<2; ++mt){
          a0[0][mt] = *reinterpret_cast<const bf16x8*>(hp[mt] + o0);
          a0[1][mt] = *reinterpret_cast<const bf16x8*>(hp[mt] + o0 + 32);
          a1[0][mt] = *reinterpret_cast<const bf16x8*>(hp[mt] + o1);
          a1[1][mt] = *reinterpret_cast<const bf16x8*>(hp[mt] + o1 + 32);
        }
      }
      #pragma unroll
      for (int c=0; c<16; ++c){
        if (c < 14){
          const int cn_ = c + 2;
          const int o = (cn_ & 7)*64 + qq*8;
          #pragma unroll
          for (int mt=0; mt<2; ++mt){
            const __hip_bfloat16* p = (cn_ < 8) ? hp[mt] : xp[mt];
            a2[0][mt] = *reinterpret_cast<const bf16x8*>(p + o);
            a2[1][mt] = *reinterpret_cast<const bf16x8*>(p + o + 32);
          }
        }
        #pragma unroll
        for (int kk=0; kk<2; ++kk){
          const int chunk = c*2 + kk;
          #pragma unroll
          for (int g=0; g<4; ++g){
            const int addr = (((g*16 + c15)*2048) + chunk*64 + qq*16) ^ lswz;
            bf16x8 bf = *reinterpret_cast<const bf16x8*>((const char*)Wlds + addr);
            acc[0][g] = __builtin_amdgcn_mfma_f32_16x16x32_bf16(a0[kk][0], bf, acc[0][g], 0,0,0);
            acc[1][g] = __builtin_amdgcn_mfma_f32_16x16x32_bf16(a0[kk][1], bf, acc[1][g], 0,0,0);
          }
        }
        #pragma unroll
        for (int kk=0; kk<2; ++kk)
          #pragma unroll
          for (int mt=0; mt<2; ++mt){
            a0[kk][mt] = a1[kk][mt];
            a1[kk][mt] = a2[kk][mt];
          }
      }

      // ---- cell epilogue: D row = qq*4+e, col = c15 ----
      #pragma unroll
      for (int mt=0; mt<2; ++mt){
        #pragma unroll
        for (int e=0; e<4; ++e){
          const int rg = rowT[mt] + qq*4 + e;
          int i, j; bool act;
          posmap(pass, rg & 63, k, Lm[mt], i, j, act);
          if (act){
            float gi = acc[mt][0][e] + bsI;
            float gf = acc[mt][1][e] + bsF;
            float gg = acc[mt][2][e] + bsG;
            float go = acc[mt][3][e] + bsO;
            float ii = 1.f/(1.f + expf(-gi));
            float ff = 1.f/(1.f + expf(-gf));
            float gt = tanhf(gg);
            float oo = 1.f/(1.f + expf(-go));
            float cn_v = ff*creg[mt][e] + ii*gt;
            creg[mt][e] = cn_v;
            float hv = oo*tanhf(cn_v);
            H[(((size_t)(cur^1)*4 + pass)*512 + rg)*512 + u] = __float2bfloat16(hv);
          }
        }
      }
    }

    // ---- group sync: 32 blocks of (pass, mhalf), one XCD ----
    __syncthreads();
    if (t == 0){
      __hip_atomic_fetch_add(&cnt[gi_base + k], 1, __ATOMIC_RELEASE, __HIP_MEMORY_SCOPE_AGENT);
      while (__hip_atomic_load(&cnt[gi_base + k], __ATOMIC_ACQUIRE, __HIP_MEMORY_SCOPE_AGENT) < 32)
        __builtin_amdgcn_s_sleep(1);
    }
    __syncthreads();

    // ---- fused projection for step k (h complete in parity cur^1) ----
    if (k < LP){
      int pi, pj; bool pact;
      posmap(pass, rP, k, LP, pi, pj, pact);
      if (pact){
        const __hip_bfloat16* hrow = H + (((size_t)(cur^1)*4 + pass)*512 + rowP)*512;
        bf16x8 hv8 = *reinterpret_cast<const bf16x8*>(hrow + lane*8);
        float hf[8];
        #pragma unroll
        for (int e=0; e<8; ++e) hf[e] = (float)hv8[e];
        float part[Tc];
        #pragma unroll
        for (int tt=0; tt<Tc; ++tt){
          const float* w = Wt + (size_t)tt*1024 + off_wt + lane*8;
          float4 w0 = *reinterpret_cast<const float4*>(w);
          float4 w1 = *reinterpret_cast<const float4*>(w + 4);
          part[tt] = hf[0]*w0.x + hf[1]*w0.y + hf[2]*w0.z + hf[3]*w0.w
                   + hf[4]*w1.x + hf[5]*w1.y + hf[6]*w1.z + hf[7]*w1.w;
        }
        #pragma unroll
        for (int tt=0; tt<Tc; ++tt){
          float s = part[tt];
          s += __shfl_xor(s, 1);  s += __shfl_xor(s, 2);  s += __shfl_xor(s, 4);
          s += __shfl_xor(s, 8);  s += __shfl_xor(s, 16); s += __shfl_xor(s, 32);
          if (lane == tt)
            atomicAdd(&pt_acc[(((size_t)bP*Tc + tt)*Sc + pi)*Sc + pj], s);
        }
      }
    }
  }
}

// labeled[b,i,j] = logsumexp_t of masked pt
__global__ void k_lse(const float* __restrict__ pt_acc, const float* __restrict__ btv,
                      const int* __restrict__ lens, float* __restrict__ lab){
  const int idx = blockIdx.x*256 + threadIdx.x;  // 32768
  const int b = idx >> 12, ij = idx & 4095;
  const int i = ij >> 6, j = ij & 63;
  const int L = lens[b];
  float vs[Tc]; float m = -INFINITY;
  #pragma unroll
  for (int t=0;t<Tc;t++){ vs[t] = pt_val(pt_acc, btv, b, t, i, j, L); m = fmaxf(m, vs[t]); }
  float ssum = 0.f;
  #pragma unroll
  for (int t=0;t<Tc;t++) ssum += expf(vs[t]-m);
  lab[idx] = m + logf(ssum);
}

// matrix-tree slogdet per batch; no-pivot LU, double, 1 barrier/iter.
__global__ __launch_bounds__(256) void k_logz(
    const float* __restrict__ lab, const int* __restrict__ lens,
    float* __restrict__ out)
{
  __shared__ double Md[64][65];
  __shared__ double part[4][64];
  __shared__ double rootv[64];
  const int b = blockIdx.x;
  const int L = lens[b];
  const int tid = threadIdx.x;
  const int c  = tid & 63;
  const int rg = tid >> 6;

  for (int r = rg; r < 64; r += 4){
    float lv = lab[((size_t)b*Sc + r)*Sc + c];
    double a;
    if (r == c) a = 0.0;
    else { a = 1e-5; if (r < L && c < L) a += exp((double)lv); }
    Md[r][c] = a;
  }
  if (rg == 0) rootv[c] = (c < L) ? exp((double)lab[((size_t)b*Sc + c)*Sc + c]) : 0.0;
  __syncthreads();
  {
    double ps = 0.0;
    for (int r = rg; r < 64; r += 4) ps += Md[r][c];
    part[rg][c] = ps;
  }
  __syncthreads();
  const double cs = part[0][c] + part[1][c] + part[2][c] + part[3][c];
  for (int r = rg; r < 64; r += 4){
    double v;
    if (r == 0) v = rootv[c];
    else { v = -Md[r][c]; if (r == c) v += cs + ((c >= L) ? 1.0 : 0.0); }
    Md[r][c] = v;
  }
  __syncthreads();

  double logdet = 0.0;
  for (int p = 0; p < 64; ++p){
    const double diag = Md[p][p];
    logdet += log(fabs(diag));
    if (c > p){
      const double inv = 1.0/diag;
      const double mpc = Md[p][c];
      for (int r = p + 1 + rg; r < 64; r += 4)
        Md[r][c] -= Md[r][p]*inv*mpc;
    }
    __syncthreads();
  }
  if (tid == 0) out[(size_t)Bc*Tc*65*65 + b] = (float)logdet;
}

// pe = _expand_matrix(masked pt)
__global__ void k_out(const float* __restrict__ pt_acc, const float* __restrict__ btv,
                      const int* __restrict__ lens, float* __restrict__ out){
  const int idx = blockIdx.x*256 + threadIdx.x;
  if (idx >= Bc*Tc*65*65) return;
  const int cc = idx % 65; int tmp = idx / 65;
  const int rr = tmp % 65; tmp /= 65;
  const int t  = tmp % Tc; const int b = tmp / Tc;
  float v;
  if (rr == cc) v = 0.f;
  else if (cc == 0) v = NEGF;
  else {
    const int i = (rr == 0) ? (cc-1) : (rr-1);
    v = pt_val(pt_acc, btv, b, t, i, cc-1, lens[b]);
  }
  out[idx] = v;
}

__global__ void k_zero_out(float* out, int n){
  int i = blockIdx.x*256 + threadIdx.x;
  if (i < n) out[i] = 0.f;
}

// ---------------------------------------------------------------------------
extern "C" void kernel_launch(void* const* d_in, const int* in_sizes, int n_in,
                              void* d_out, int out_size, void* d_ws, size_t ws_size,
                              hipStream_t stream)
{
  (void)in_sizes; (void)n_in;
  const int*   lens  = (const int*)  d_in[2];
  const float* sv    = (const float*)d_in[3];
  const float* Wih_f = (const float*)d_in[5];
  const float* Whh_f = (const float*)d_in[6];
  const float* bih_f = (const float*)d_in[7];
  const float* bhh_f = (const float*)d_in[8];
  const float* Wih_b = (const float*)d_in[9];
  const float* Whh_b = (const float*)d_in[10];
  const float* bih_b = (const float*)d_in[11];
  const float* bhh_b = (const float*)d_in[12];
  const float* Wt    = (const float*)d_in[13];
  const float* btv   = (const float*)d_in[14];

  const size_t SVB  = (size_t)Bc*TRIc*Hc*2;       // 17.0 MB bf16
  const size_t WPB  = (size_t)2*32*64*1024*2;     // 8.39 MB bf16
  const size_t PT   = (size_t)Bc*Tc*Sc*Sc*4;      // 2.23 MB
  const size_t HB   = (size_t)2*4*512*512*2;      // 4.19 MB bf16
  const size_t LAB  = (size_t)Bc*Sc*Sc*4;         // 131 KB
  const size_t CNT  = 2048;
  const size_t NEED = SVB + WPB + PT + HB + LAB + CNT + 8192;

  if (ws_size < NEED) {
    k_zero_out<<<dim3((out_size+255)/256), 256, 0, stream>>>((float*)d_out, out_size);
    return;
  }

  char* base = (char*)d_ws;
  size_t off = 0;
  auto take = [&](size_t bytes)->char*{
    char* r = base + off; off += (bytes + 255) & ~(size_t)255; return r; };

  __hip_bfloat16* svb = (__hip_bfloat16*)take(SVB);
  __hip_bfloat16* Wp  = (__hip_bfloat16*)take(WPB);
  float* pt_acc = (float*)take(PT);
  __hip_bfloat16* H = (__hip_bfloat16*)take(HB);
  float* lab = (float*)take(LAB);
  int*   cnt = (int*)take(CNT);

  // zero pt_acc + H + lab + cnt (contiguous)
  (void)hipMemsetAsync(pt_acc, 0, PT + HB + LAB + CNT, stream);

  k_cvt <<<dim3(8320), 256, 0, stream>>>(sv, svb, 2129920);
  k_pack<<<dim3(4096), 256, 0, stream>>>(Whh_f, Wih_f, Whh_b, Wih_b, Wp);

  k_persist<<<dim3(256), 512, 0, stream>>>(Wp, bih_f, bhh_f, bih_b, bhh_b,
                                           svb, Wt, lens, H, pt_acc, cnt);

  k_lse <<<dim3(128), 256, 0, stream>>>(pt_acc, btv, lens, lab);
  k_logz<<<dim3(Bc), 256, 0, stream>>>(lab, lens, (float*)d_out);
  k_out <<<dim3((Bc*Tc*65*65 + 255)/256), 256, 0, stream>>>(pt_acc, btv, lens, (float*)d_out);
}

// Round 8
// 1777.705 us; speedup vs baseline: 1.7526x; 1.7526x over previous
//
#include <hip/hip_runtime.h>
#include <hip/hip_bf16.h>
#include <math.h>

#define NEGF (-1000000000.0f)

constexpr int Bc = 8;
constexpr int Sc = 64;
constexpr int Hc = 512;
constexpr int Tc = 17;
constexpr int TRIc = Sc*(Sc+1)/2;     // 2080
constexpr int PTN  = Bc*Tc*Sc*Sc;     // elements per pt part

typedef __bf16 bf16x8 __attribute__((ext_vector_type(8)));
typedef float  f32x4  __attribute__((ext_vector_type(4)));

__device__ __forceinline__ int tri_idx(int i, int j){
  return i*Sc - (i*(i-1))/2 + (j - i);
}

// (i,j) position + activity for (pass, row r, step k, length L)
__device__ __forceinline__ void posmap(int pass, int r, int k, int L,
                                       int& i, int& j, bool& act){
  if      (pass == 0){ act = (r < L - k);            i = r;     j = L - 1 - k; }
  else if (pass == 1){ act = (r < L - k);            i = r;     j = r + k;     }
  else if (pass == 2){ act = (r >= k) && (r < L);    i = r - k; j = r;         }
  else               { act = (r >= k) && (r < L);    i = k;     j = r;         }
  if (!act){ i = 0; j = 0; }
}

// masked pt value; pt split in 4 parts of PTN elements
__device__ __forceinline__ float pt_val(const float* __restrict__ pt_acc,
                                        const float* __restrict__ btv,
                                        int b, int t, int i, int j, int L){
  const bool masked = (i > j) || (j >= L) ||
                      (t < Tc-1 && i == j) || (t == Tc-1 && i < j);
  if (masked) return NEGF;
  const size_t idx = (((size_t)b*Tc + t)*Sc + i)*Sc + j;
  return pt_acc[idx] + pt_acc[PTN + idx] + pt_acc[2*PTN + idx]
       + pt_acc[3*PTN + idx] + btv[t];
}

// ---------------------------------------------------------------------------
__global__ __launch_bounds__(256) void k_cvt(const float* __restrict__ s,
                                             __hip_bfloat16* __restrict__ d, int n4){
  int i = blockIdx.x*256 + threadIdx.x;
  if (i >= n4) return;
  float4 v = reinterpret_cast<const float4*>(s)[i];
  union { __hip_bfloat16 h[4]; ushort4 u; } p;
  p.h[0] = __float2bfloat16(v.x); p.h[1] = __float2bfloat16(v.y);
  p.h[2] = __float2bfloat16(v.z); p.h[3] = __float2bfloat16(v.w);
  reinterpret_cast<ushort4*>(d)[i] = p.u;
}

// ---------------------------------------------------------------------------
// Weight prepack: Wp[wset][us(32)][row(64)][k(1024)] bf16
//   row = g*16 + uu  <->  source row g*512 + us*16 + uu
//   k < 512 -> Whh[srow][k] ; k >= 512 -> Wih[srow][k-512]
// ---------------------------------------------------------------------------
__global__ __launch_bounds__(256) void k_pack(
    const float* __restrict__ Whh_f, const float* __restrict__ Wih_f,
    const float* __restrict__ Whh_b, const float* __restrict__ Wih_b,
    __hip_bfloat16* __restrict__ Wp)
{
  int idx = blockIdx.x*256 + threadIdx.x;   // 1,048,576 quads
  int k4  = idx & 255;
  int row = (idx >> 8) & 63;
  int us  = (idx >> 14) & 31;
  int ws  = idx >> 19;
  int g = row >> 4, uu = row & 15;
  int srow = g*512 + us*16 + uu;
  int k = k4*4;
  const float* src;
  if (ws == 0) src = (k < 512) ? Whh_f : Wih_f;
  else         src = (k < 512) ? Whh_b : Wih_b;
  float4 v = *reinterpret_cast<const float4*>(src + (size_t)srow*512 + (k & 511));
  union { __hip_bfloat16 h[4]; ushort4 u; } p;
  p.h[0] = __float2bfloat16(v.x); p.h[1] = __float2bfloat16(v.y);
  p.h[2] = __float2bfloat16(v.z); p.h[3] = __float2bfloat16(v.w);
  *reinterpret_cast<ushort4*>(Wp + (size_t)idx*4) = p.u;
}

// ---------------------------------------------------------------------------
// One lockstep LSTM step, all 4 passes. grid 512 blocks, 512 threads.
// bid = us*16 + gid; gid: pp=gid&1 (weight set; XCD-pins one set per XCD),
// bq=(gid>>1)&3, sub=gid>>3; pass = pp ? (sub?2:1) : (sub?3:0).
// Block tile: M=128 rows (2 batches), N=64 gate-cols (4 gates x 16 units),
// K=1024 (h|x). Wave w: rows w*16..w*16+15, all N.
// ---------------------------------------------------------------------------
__global__ __launch_bounds__(512,4) void k_step4(
    const __hip_bfloat16* __restrict__ Wp,
    const float* __restrict__ bih_f, const float* __restrict__ bhh_f,
    const float* __restrict__ bih_b, const float* __restrict__ bhh_b,
    const __hip_bfloat16* __restrict__ svb, const float* __restrict__ Wt,
    const int* __restrict__ lens,
    __hip_bfloat16* __restrict__ H, float* __restrict__ C,
    float* __restrict__ pt_acc, int k)
{
  const int bid = blockIdx.x;
  const int us  = bid >> 4;
  const int gid = bid & 15;
  const int pp  = gid & 1;            // 0: F-params, 1: B-params
  const int bq  = (gid >> 1) & 3;     // batch pair
  const int sub = gid >> 3;
  const int pass = pp ? (sub ? 2 : 1) : (sub ? 3 : 0);

  const int L0 = lens[bq*2], L1 = lens[bq*2+1];
  if (k >= max(L0, L1)) return;

  const float* b1 = pp ? bih_b : bih_f;
  const float* b2 = pp ? bhh_b : bhh_f;
  const int off_wt = (pass==0 || pass==2) ? 512 : 0;

  const int t = threadIdx.x, lane = t & 63, wv = t >> 6;
  const int c15 = lane & 15, qq = lane >> 4;
  const int b_local = wv >> 2;                 // 0..1
  const int mrow = (wv & 3)*16;                // row base within batch
  const int b = bq*2 + b_local;
  const int L = b_local ? L1 : L0;

  __shared__ __hip_bfloat16 Ws[2][64*72];      // W K-chunk dbuf, padded rows
  __shared__ float hbuf[128][17];              // h out (fp32)
  __shared__ float Wts[17][16];                // Wt slice

  if (t < 272){
    int tt = t >> 4, u = t & 15;
    Wts[tt][u] = Wt[(size_t)tt*1024 + off_wt + us*16 + u];
  }

  const int cur = k & 1;
  const __hip_bfloat16* Hbase = H + ((size_t)cur*4 + pass)*512*512;
  __hip_bfloat16*       Hnx   = H + ((size_t)(cur^1)*4 + pass)*512*512;
  float* Cb = C + ((size_t)pass*8 + b)*64*512;

  // A-operand pointers (lane row = mrow + c15 within batch)
  const int arow = mrow + c15;
  int ai, aj; bool aact;
  posmap(pass, arow, k, L, ai, aj, aact);
  const __hip_bfloat16* hp = Hbase + ((size_t)b*64 + arow)*512;
  const __hip_bfloat16* xp = svb + ((size_t)b*TRIc + tri_idx(ai, aj))*512;

  const __hip_bfloat16* Wpb = Wp + (((size_t)pp*32 + us)*64)*1024;

  int4 stg;
  auto ldg = [&](int c){
    stg = *reinterpret_cast<const int4*>(Wpb + (size_t)(t>>3)*1024 + c*64 + (t&7)*8);
  };
  auto stl = [&](int buf){
    *reinterpret_cast<int4*>(&Ws[buf][(t>>3)*72 + (t&7)*8]) = stg;
  };

  bf16x8 a[2], an[2];
  auto lda = [&](int c, bf16x8 (&dst)[2]){
    const __hip_bfloat16* p = (c < 8) ? hp : xp;
    const int o = (c & 7)*64 + qq*8;
    dst[0] = *reinterpret_cast<const bf16x8*>(p + o);
    dst[1] = *reinterpret_cast<const bf16x8*>(p + o + 32);
  };

  f32x4 acc[4];                                // per gate
  #pragma unroll
  for (int g=0; g<4; ++g) acc[g] = f32x4{0.f,0.f,0.f,0.f};

  ldg(0); lda(0, a); stl(0);
  __syncthreads();

  for (int c=0; c<16; ++c){
    if (c < 15){ ldg(c+1); lda(c+1, an); }
    const int buf = c & 1;
    #pragma unroll
    for (int kk=0; kk<2; ++kk){
      #pragma unroll
      for (int g=0; g<4; ++g){
        bf16x8 bf = *reinterpret_cast<const bf16x8*>(
            &Ws[buf][(g*16 + c15)*72 + kk*32 + qq*8]);
        acc[g] = __builtin_amdgcn_mfma_f32_16x16x32_bf16(a[kk], bf, acc[g], 0,0,0);
      }
    }
    if (c < 15){
      stl(buf ^ 1);
      a[0] = an[0]; a[1] = an[1];
    }
    __syncthreads();
  }

  // ---- cell epilogue: D row = qq*4+e (seq row), col = c15 (unit) ----------
  const int u = us*16 + c15;
  const float bsI = b1[u]        + b2[u];
  const float bsF = b1[512 + u]  + b2[512 + u];
  const float bsG = b1[1024 + u] + b2[1024 + u];
  const float bsO = b1[1536 + u] + b2[1536 + u];

  #pragma unroll
  for (int e=0; e<4; ++e){
    const int r = mrow + qq*4 + e;             // row within batch
    int i, j; bool act;
    posmap(pass, r, k, L, i, j, act);
    float hv = 0.f;
    if (act){
      float gi = acc[0][e] + bsI;
      float gf = acc[1][e] + bsF;
      float gg = acc[2][e] + bsG;
      float go = acc[3][e] + bsO;
      float ii = 1.f/(1.f + expf(-gi));
      float ff = 1.f/(1.f + expf(-gf));
      float gt = tanhf(gg);
      float oo = 1.f/(1.f + expf(-go));
      float cn = ff*Cb[(size_t)r*512 + u] + ii*gt;
      hv = oo*tanhf(cn);
      Cb[(size_t)r*512 + u] = cn;
      Hnx[((size_t)b*64 + r)*512 + u] = __float2bfloat16(hv);
    }
    hbuf[wv*16 + qq*4 + e][c15] = hv;
  }
  __syncthreads();

  // ---- projection: pt[b,tt,i,j] += h[row][16u] . Wts[tt][16u] -------------
  {
    const int rowi = t >> 2;                   // 0..127
    const int q    = t & 3;                    // unit quarter
    const int b_p  = bq*2 + (rowi >> 6);
    const int r_p  = rowi & 63;
    const int L_p  = (rowi >> 6) ? L1 : L0;
    int pi, pj; bool pact;
    posmap(pass, r_p, k, L_p, pi, pj, pact);
    if (pact){
      float h0 = hbuf[rowi][q*4+0], h1 = hbuf[rowi][q*4+1];
      float h2 = hbuf[rowi][q*4+2], h3 = hbuf[rowi][q*4+3];
      float* ptp = pt_acc + (size_t)(us & 3)*PTN;
      #pragma unroll
      for (int tt=0; tt<Tc; ++tt){
        float s = h0*Wts[tt][q*4] + h1*Wts[tt][q*4+1]
                + h2*Wts[tt][q*4+2] + h3*Wts[tt][q*4+3];
        s += __shfl_xor(s, 1);
        s += __shfl_xor(s, 2);
        if (q == 0)
          atomicAdd(&ptp[(((size_t)b_p*Tc + tt)*Sc + pi)*Sc + pj], s);
      }
    }
  }
}

// labeled[b,i,j] = logsumexp_t of masked pt
__global__ void k_lse(const float* __restrict__ pt_acc, const float* __restrict__ btv,
                      const int* __restrict__ lens, float* __restrict__ lab){
  const int idx = blockIdx.x*256 + threadIdx.x;  // 32768
  const int b = idx >> 12, ij = idx & 4095;
  const int i = ij >> 6, j = ij & 63;
  const int L = lens[b];
  float vs[Tc]; float m = -INFINITY;
  #pragma unroll
  for (int t=0;t<Tc;t++){ vs[t] = pt_val(pt_acc, btv, b, t, i, j, L); m = fmaxf(m, vs[t]); }
  float ssum = 0.f;
  #pragma unroll
  for (int t=0;t<Tc;t++) ssum += expf(vs[t]-m);
  lab[idx] = m + logf(ssum);
}

// matrix-tree slogdet per batch; no-pivot LU (leading minors positive), double.
__global__ __launch_bounds__(256) void k_logz(
    const float* __restrict__ lab, const int* __restrict__ lens,
    float* __restrict__ out)
{
  __shared__ double Md[64][65];
  __shared__ double part[4][64];
  __shared__ double rootv[64];
  const int b = blockIdx.x;
  const int L = lens[b];
  const int tid = threadIdx.x;
  const int c  = tid & 63;
  const int rg = tid >> 6;

  for (int r = rg; r < 64; r += 4){
    float lv = lab[((size_t)b*Sc + r)*Sc + c];
    double a;
    if (r == c) a = 0.0;
    else { a = 1e-5; if (r < L && c < L) a += exp((double)lv); }
    Md[r][c] = a;
  }
  if (rg == 0) rootv[c] = (c < L) ? exp((double)lab[((size_t)b*Sc + c)*Sc + c]) : 0.0;
  __syncthreads();
  {
    double ps = 0.0;
    for (int r = rg; r < 64; r += 4) ps += Md[r][c];
    part[rg][c] = ps;
  }
  __syncthreads();
  const double cs = part[0][c] + part[1][c] + part[2][c] + part[3][c];
  for (int r = rg; r < 64; r += 4){
    double v;
    if (r == 0) v = rootv[c];
    else { v = -Md[r][c]; if (r == c) v += cs + ((c >= L) ? 1.0 : 0.0); }
    Md[r][c] = v;
  }
  __syncthreads();

  double logdet = 0.0;
  for (int p = 0; p < 64; ++p){
    const double diag = Md[p][p];
    logdet += log(fabs(diag));
    if (c > p){
      const double inv = 1.0/diag;
      const double mpc = Md[p][c];
      for (int r = p + 1 + rg; r < 64; r += 4)
        Md[r][c] -= Md[r][p]*inv*mpc;
    }
    __syncthreads();
  }
  if (tid == 0) out[(size_t)Bc*Tc*65*65 + b] = (float)logdet;
}

// pe = _expand_matrix(masked pt)
__global__ void k_out(const float* __restrict__ pt_acc, const float* __restrict__ btv,
                      const int* __restrict__ lens, float* __restrict__ out){
  const int idx = blockIdx.x*256 + threadIdx.x;
  if (idx >= Bc*Tc*65*65) return;
  const int cc = idx % 65; int tmp = idx / 65;
  const int rr = tmp % 65; tmp /= 65;
  const int t  = tmp % Tc; const int b = tmp / Tc;
  float v;
  if (rr == cc) v = 0.f;
  else if (cc == 0) v = NEGF;
  else {
    const int i = (rr == 0) ? (cc-1) : (rr-1);
    v = pt_val(pt_acc, btv, b, t, i, cc-1, lens[b]);
  }
  out[idx] = v;
}

__global__ void k_zero_out(float* out, int n){
  int i = blockIdx.x*256 + threadIdx.x;
  if (i < n) out[i] = 0.f;
}

// ---------------------------------------------------------------------------
extern "C" void kernel_launch(void* const* d_in, const int* in_sizes, int n_in,
                              void* d_out, int out_size, void* d_ws, size_t ws_size,
                              hipStream_t stream)
{
  (void)in_sizes; (void)n_in;
  const int*   lens  = (const int*)  d_in[2];
  const float* sv    = (const float*)d_in[3];
  const float* Wih_f = (const float*)d_in[5];
  const float* Whh_f = (const float*)d_in[6];
  const float* bih_f = (const float*)d_in[7];
  const float* bhh_f = (const float*)d_in[8];
  const float* Wih_b = (const float*)d_in[9];
  const float* Whh_b = (const float*)d_in[10];
  const float* bih_b = (const float*)d_in[11];
  const float* bhh_b = (const float*)d_in[12];
  const float* Wt    = (const float*)d_in[13];
  const float* btv   = (const float*)d_in[14];

  const size_t SVB  = (size_t)Bc*TRIc*Hc*2;       // 17.0 MB bf16
  const size_t WPB  = (size_t)2*32*64*1024*2;     // 8.39 MB bf16
  const size_t PT4  = (size_t)4*PTN*4;            // 8.92 MB (4 parts)
  const size_t HB   = (size_t)2*4*512*512*2;      // 4.19 MB bf16
  const size_t CB   = (size_t)4*8*64*512*4;       // 4.19 MB fp32
  const size_t LAB  = (size_t)Bc*Sc*Sc*4;         // 131 KB
  const size_t NEED = SVB + WPB + PT4 + HB + CB + LAB + 8192;

  if (ws_size < NEED) {
    k_zero_out<<<dim3((out_size+255)/256), 256, 0, stream>>>((float*)d_out, out_size);
    return;
  }

  char* base = (char*)d_ws;
  size_t off = 0;
  auto take = [&](size_t bytes)->char*{
    char* r = base + off; off += (bytes + 255) & ~(size_t)255; return r; };

  __hip_bfloat16* svb = (__hip_bfloat16*)take(SVB);
  __hip_bfloat16* Wp  = (__hip_bfloat16*)take(WPB);
  float* pt_acc = (float*)take(PT4);
  __hip_bfloat16* H = (__hip_bfloat16*)take(HB);
  float* C   = (float*)take(CB);
  float* lab = (float*)take(LAB);

  // zero pt parts + H + C (contiguous)
  (void)hipMemsetAsync(pt_acc, 0, PT4 + HB + CB, stream);

  k_cvt <<<dim3(8320), 256, 0, stream>>>(sv, svb, 2129920);
  k_pack<<<dim3(4096), 256, 0, stream>>>(Whh_f, Wih_f, Whh_b, Wih_b, Wp);

  for (int k=0; k<Sc; k++)
    k_step4<<<dim3(512), 512, 0, stream>>>(Wp, bih_f, bhh_f, bih_b, bhh_b,
                                           svb, Wt, lens, H, C, pt_acc, k);

  k_lse <<<dim3(128), 256, 0, stream>>>(pt_acc, btv, lens, lab);
  k_logz<<<dim3(Bc), 256, 0, stream>>>(lab, lens, (float*)d_out);
  k_out <<<dim3((Bc*Tc*65*65 + 255)/256), 256, 0, stream>>>(pt_acc, btv, lens, (float*)d_out);
}